// Round 2
// baseline (202.148 us; speedup 1.0000x reference)
//
#include <hip/hip_runtime.h>

static constexpr int NS    = 1024;   // N
static constexpr int KR    = 17;     // K
static constexpr int NROWS = NS * KR;

__device__ inline float wave_sum(float v) {
#pragma unroll
    for (int s = 32; s > 0; s >>= 1) v += __shfl_xor(v, s, 64);
    return v;
}
__device__ inline float wave_max(float v) {
#pragma unroll
    for (int s = 32; s > 0; s >>= 1) v = fmaxf(v, __shfl_xor(v, s, 64));
    return v;
}

// One 64-lane wave per row of length W.
//   lesser = all(pred < 3)  ==  max(pred) < 3      (wave-uniform branch!)
//   BCE rows: mean( max(p,0) + log(1+e^-|p|) - p*g )
//   KLD rows: mean-folded  (T1 - T2)/S - log(S) + lse
//     e_i = exp(10*g_i)  (gt in [0,1): no max-shift needed, e <= 2.2e4)
//     S = sum e, T1 = sum e*10g, T2 = sum e*p, lse = logsumexp(pred)
template <int W>
__device__ __forceinline__ void row_body(
    const float* __restrict__ pred, const float* __restrict__ gt,
    float* __restrict__ loss, int* __restrict__ flag, int row, int lane) {
    const float2* p2 = (const float2*)(pred + (size_t)row * W);
    const float2* g2 = (const float2*)(gt   + (size_t)row * W);
    constexpr int EP = W / 128;  // float2 per lane (3 for 384, 4 for 512)

    // pass 1: max(pred) only
    float2 pv[EP];
    float mp = -1e30f;
#pragma unroll
    for (int j = 0; j < EP; ++j) {
        pv[j] = p2[lane + 64 * j];
        mp = fmaxf(mp, fmaxf(pv[j].x, pv[j].y));
    }
    mp = wave_max(mp);
    const float inv = 1.0f / (float)W;

    if (mp < 3.0f) {  // BCE branch (wave-uniform)
        float bce = 0.f;
#pragma unroll
        for (int j = 0; j < EP; ++j) {
            float2 gvv = g2[lane + 64 * j];
            float pe[2] = {pv[j].x, pv[j].y};
            float ge[2] = {gvv.x, gvv.y};
#pragma unroll
            for (int t = 0; t < 2; ++t) {
                float p = pe[t];
                bce += fmaxf(p, 0.f) + __logf(1.f + __expf(-fabsf(p))) - p * ge[t];
            }
        }
        bce = wave_sum(bce);
        if (lane == 0) { loss[row] = bce * inv; flag[row] = 1; }
    } else {          // KLD branch
        float sp = 0.f, S = 0.f, T1 = 0.f, T2 = 0.f;
#pragma unroll
        for (int j = 0; j < EP; ++j) {
            float2 gvv = g2[lane + 64 * j];
            float pe[2] = {pv[j].x, pv[j].y};
            float ge[2] = {gvv.x, gvv.y};
#pragma unroll
            for (int t = 0; t < 2; ++t) {
                float p = pe[t];
                float g10 = 10.0f * ge[t];
                sp += __expf(p - mp);
                float e = __expf(g10);
                S  += e;
                T1 += e * g10;
                T2 += e * p;
            }
        }
        sp = wave_sum(sp);
        S  = wave_sum(S);
        T1 = wave_sum(T1);
        T2 = wave_sum(T2);
        if (lane == 0) {
            float lse = mp + __logf(sp);
            loss[row] = ((T1 - T2) / S - __logf(S) + lse) * inv;
            flag[row] = 0;
        }
    }
}

static constexpr int XB = (NROWS + 3) / 4;  // blocks for the X half (4 waves/block)

__global__ __launch_bounds__(256) void row_loss_fused(
    const float* __restrict__ px, const float* __restrict__ gx,
    const float* __restrict__ py, const float* __restrict__ gy,
    float* __restrict__ lx, int* __restrict__ fx,
    float* __restrict__ ly, int* __restrict__ fy) {
    const int widx = threadIdx.x >> 6;
    const int lane = threadIdx.x & 63;
    if ((int)blockIdx.x < XB) {
        int row = blockIdx.x * 4 + widx;
        if (row < NROWS) row_body<384>(px, gx, lx, fx, row, lane);
    } else {
        int row = (blockIdx.x - XB) * 4 + widx;
        if (row < NROWS) row_body<512>(py, gy, ly, fy, row, lane);
    }
}

// Single block: per-sample stable-argsort dot (KLD rows first in original
// order, then BCE rows) against weights, then deterministic block sum, /K.
__global__ __launch_bounds__(256) void combine_reduce_kernel(
    const float* __restrict__ lx, const int* __restrict__ fx,
    const float* __restrict__ ly, const int* __restrict__ fy,
    const float* __restrict__ w, float* __restrict__ out) {
    float acc = 0.f;
    for (int n = threadIdx.x; n < NS; n += 256) {
        const float* wn = w + n * KR;
        {
            const float* l = lx + n * KR;
            const int*   f = fx + n * KR;
            int pos = 0;
            for (int k = 0; k < KR; ++k) if (!f[k]) acc += l[k] * wn[pos++];
            for (int k = 0; k < KR; ++k) if (f[k])  acc += l[k] * wn[pos++];
        }
        {
            const float* l = ly + n * KR;
            const int*   f = fy + n * KR;
            int pos = 0;
            for (int k = 0; k < KR; ++k) if (!f[k]) acc += l[k] * wn[pos++];
            for (int k = 0; k < KR; ++k) if (f[k])  acc += l[k] * wn[pos++];
        }
    }
    acc = wave_sum(acc);
    __shared__ float wsm[4];
    if ((threadIdx.x & 63) == 0) wsm[threadIdx.x >> 6] = acc;
    __syncthreads();
    if (threadIdx.x == 0)
        out[0] = (wsm[0] + wsm[1] + wsm[2] + wsm[3]) * (1.0f / (float)KR);
}

extern "C" void kernel_launch(void* const* d_in, const int* in_sizes, int n_in,
                              void* d_out, int out_size, void* d_ws, size_t ws_size,
                              hipStream_t stream) {
    const float* pred_x = (const float*)d_in[0];
    const float* pred_y = (const float*)d_in[1];
    const float* gt_x   = (const float*)d_in[2];
    const float* gt_y   = (const float*)d_in[3];
    const float* tw     = (const float*)d_in[4];

    // workspace: lx | ly | fx | fy  (all 4 B elems)
    float* lx = (float*)d_ws;
    float* ly = lx + NROWS;
    int*   fx = (int*)(ly + NROWS);
    int*   fy = fx + NROWS;

    row_loss_fused<<<2 * XB, 256, 0, stream>>>(pred_x, gt_x, pred_y, gt_y,
                                               lx, fx, ly, fy);
    combine_reduce_kernel<<<1, 256, 0, stream>>>(lx, fx, ly, fy, tw,
                                                 (float*)d_out);
}

// Round 3
// 149.438 us; speedup vs baseline: 1.3527x; 1.3527x over previous
//
#include <hip/hip_runtime.h>

static constexpr int NS    = 1024;   // N
static constexpr int KR    = 17;     // K
static constexpr int NROWS = NS * KR;

__device__ inline float wave_sum(float v) {
#pragma unroll
    for (int s = 32; s > 0; s >>= 1) v += __shfl_xor(v, s, 64);
    return v;
}
__device__ inline float wave_max(float v) {
#pragma unroll
    for (int s = 32; s > 0; s >>= 1) v = fmaxf(v, __shfl_xor(v, s, 64));
    return v;
}

// One 64-lane wave per row of length W.
//   lesser = all(pred < 3)  ==  max(pred) < 3    (wave-uniform branch)
//   BCE rows: mean( max(p,0) - p*g ) + mean( log(1+e^-|p|) )
//     second term via log of per-lane product: prod(1+e^-|p|) <= 2^8, safe.
//   KLD rows: mean-folded  (T1 - T2)/S - log(S) + lse
//     e_i = exp(10*g_i)  (g in [0,1): S <= 512*e^10 ~ 1.1e7, fp32-safe unshifted)
template <int W>
__global__ __launch_bounds__(256) void row_loss_kernel(
    const float* __restrict__ pred, const float* __restrict__ gt,
    float* __restrict__ loss, int* __restrict__ flag) {
    const int row  = (int)((blockIdx.x * (unsigned)blockDim.x + threadIdx.x) >> 6);
    const int lane = threadIdx.x & 63;
    if (row >= NROWS) return;

    const float2* p2 = (const float2*)(pred + (size_t)row * W);
    const float2* g2 = (const float2*)(gt   + (size_t)row * W);
    constexpr int EP = W / 128;  // float2 per lane (3 for 384, 4 for 512)

    // Issue ALL loads up front (max memory-level parallelism), then reduce.
    float2 pv[EP], gv[EP];
#pragma unroll
    for (int j = 0; j < EP; ++j) {
        pv[j] = p2[lane + 64 * j];
        gv[j] = g2[lane + 64 * j];
    }

    float mp = -1e30f;
#pragma unroll
    for (int j = 0; j < EP; ++j) mp = fmaxf(mp, fmaxf(pv[j].x, pv[j].y));
    mp = wave_max(mp);
    const float inv = 1.0f / (float)W;

    if (mp < 3.0f) {  // BCE branch (wave-uniform)
        float lin = 0.f, prod = 1.f;
#pragma unroll
        for (int j = 0; j < EP; ++j) {
            float pe[2] = {pv[j].x, pv[j].y};
            float ge[2] = {gv[j].x, gv[j].y};
#pragma unroll
            for (int t = 0; t < 2; ++t) {
                float p = pe[t];
                lin  += fmaxf(p, 0.f) - p * ge[t];
                prod *= 1.f + __expf(-fabsf(p));
            }
        }
        float v = wave_sum(lin + __logf(prod));
        if (lane == 0) { loss[row] = v * inv; flag[row] = 1; }
    } else {          // KLD branch
        float sp = 0.f, S = 0.f, T1 = 0.f, T2 = 0.f;
#pragma unroll
        for (int j = 0; j < EP; ++j) {
            float pe[2] = {pv[j].x, pv[j].y};
            float ge[2] = {gv[j].x, gv[j].y};
#pragma unroll
            for (int t = 0; t < 2; ++t) {
                float p   = pe[t];
                float g10 = 10.0f * ge[t];
                sp += __expf(p - mp);
                float e = __expf(g10);
                S  += e;
                T1 += e * g10;
                T2 += e * p;
            }
        }
        sp = wave_sum(sp);
        S  = wave_sum(S);
        T1 = wave_sum(T1);
        T2 = wave_sum(T2);
        if (lane == 0) {
            float lse = mp + __logf(sp);
            loss[row] = ((T1 - T2) / S - __logf(S) + lse) * inv;
            flag[row] = 0;
        }
    }
}

// One wave per sample. Stable-argsort permutation in closed form via ballot:
// KLD rows (f==0) keep original order first, then BCE rows (f==1).
//   pos(k) = f[k] ? nKld + popc(bceMask & below(k)) : popc(kldMask & below(k))
__global__ __launch_bounds__(256) void combine_kernel(
    const float* __restrict__ lx, const int* __restrict__ fx,
    const float* __restrict__ ly, const int* __restrict__ fy,
    const float* __restrict__ w, float* __restrict__ partial) {
    const int widx = threadIdx.x >> 6;
    const int lane = threadIdx.x & 63;
    const int n = blockIdx.x * 4 + widx;  // grid = NS/4 blocks
    const float* wn = w + n * KR;
    const unsigned long long below = (1ULL << lane) - 1ULL;

    float acc = 0.f;
    {
        int f = 1; float l = 0.f;
        if (lane < KR) { f = fx[n * KR + lane]; l = lx[n * KR + lane]; }
        unsigned long long mk = __ballot(lane < KR && !f);  // KLD rows
        int nk = __popcll(mk);
        int pos = f ? nk + __popcll(~mk & below) : __popcll(mk & below);
        if (lane < KR) acc += l * wn[pos];
    }
    {
        int f = 1; float l = 0.f;
        if (lane < KR) { f = fy[n * KR + lane]; l = ly[n * KR + lane]; }
        unsigned long long mk = __ballot(lane < KR && !f);
        int nk = __popcll(mk);
        int pos = f ? nk + __popcll(~mk & below) : __popcll(mk & below);
        if (lane < KR) acc += l * wn[pos];
    }
    acc = wave_sum(acc);
    __shared__ float s[4];
    if (lane == 0) s[widx] = acc;
    __syncthreads();
    if (threadIdx.x == 0)
        partial[blockIdx.x] = s[0] + s[1] + s[2] + s[3];
}

// Deterministic final reduction of NS/4 = 256 partials, /K.
__global__ __launch_bounds__(256) void final_reduce_kernel(
    const float* __restrict__ partial, float* __restrict__ out) {
    float v = partial[threadIdx.x];  // exactly 256 partials
    v = wave_sum(v);
    __shared__ float s[4];
    if ((threadIdx.x & 63) == 0) s[threadIdx.x >> 6] = v;
    __syncthreads();
    if (threadIdx.x == 0)
        out[0] = (s[0] + s[1] + s[2] + s[3]) * (1.0f / (float)KR);
}

extern "C" void kernel_launch(void* const* d_in, const int* in_sizes, int n_in,
                              void* d_out, int out_size, void* d_ws, size_t ws_size,
                              hipStream_t stream) {
    const float* pred_x = (const float*)d_in[0];
    const float* pred_y = (const float*)d_in[1];
    const float* gt_x   = (const float*)d_in[2];
    const float* gt_y   = (const float*)d_in[3];
    const float* tw     = (const float*)d_in[4];

    // workspace: lx | ly | fx | fy | partial  (all 4 B elems)
    float* lx      = (float*)d_ws;
    float* ly      = lx + NROWS;
    int*   fx      = (int*)(ly + NROWS);
    int*   fy      = fx + NROWS;
    float* partial = (float*)(fy + NROWS);

    const int row_blocks = (NROWS + 3) / 4;  // 4 waves (rows) per block
    row_loss_kernel<384><<<row_blocks, 256, 0, stream>>>(pred_x, gt_x, lx, fx);
    row_loss_kernel<512><<<row_blocks, 256, 0, stream>>>(pred_y, gt_y, ly, fy);
    combine_kernel<<<NS / 4, 256, 0, stream>>>(lx, fx, ly, fy, tw, partial);
    final_reduce_kernel<<<1, 256, 0, stream>>>(partial, (float*)d_out);
}